// Round 4
// baseline (305.067 us; speedup 1.0000x reference)
//
#include <hip/hip_runtime.h>
#include <stdint.h>

#define SD 128
#define SH 128
#define SW 128
#define BATCH 2
#define CCH 64
#define KV 27

typedef __attribute__((ext_vector_type(4))) float f32x4;
typedef __attribute__((ext_vector_type(8))) short s16x8;

__device__ __forceinline__ unsigned short f2bf_rne(float f) {
    union { float f; unsigned int u; } v; v.f = f;
    unsigned int u = v.u;
    return (unsigned short)((u + 0x7FFFu + ((u >> 16) & 1u)) >> 16);
}

__device__ __forceinline__ s16x8 pack_bf8(float4 a, float4 b) {
    s16x8 o;
    o[0] = (short)f2bf_rne(a.x); o[1] = (short)f2bf_rne(a.y);
    o[2] = (short)f2bf_rne(a.z); o[3] = (short)f2bf_rne(a.w);
    o[4] = (short)f2bf_rne(b.x); o[5] = (short)f2bf_rne(b.y);
    o[6] = (short)f2bf_rne(b.z); o[7] = (short)f2bf_rne(b.w);
    return o;
}

// features f32 -> bf16 (optional, only if workspace allows)
__global__ void k_f2bf(const float4* __restrict__ in, ushort4* __restrict__ out, int n4) {
    int i = blockIdx.x * blockDim.x + threadIdx.x;
    if (i >= n4) return;
    float4 a = in[i];
    ushort4 o;
    o.x = f2bf_rne(a.x); o.y = f2bf_rne(a.y);
    o.z = f2bf_rne(a.z); o.w = f2bf_rne(a.w);
    out[i] = o;
}

// W [27][64][64] f32 -> bf16, B-fragment layout: elem ((k*8 + ci/8)*64 + co)*8 + ci%8
__global__ void k_wprep(const float* __restrict__ W, unsigned short* __restrict__ Wt) {
    int idx = blockIdx.x * blockDim.x + threadIdx.x;
    if (idx >= KV * CCH * CCH) return;
    int k = idx / (CCH * CCH);
    int rem = idx - k * CCH * CCH;
    int ci = rem >> 6, co = rem & 63;
    int d = ((k * 8 + (ci >> 3)) * 64 + co) * 8 + (ci & 7);
    Wt[d] = f2bf_rne(W[idx]);
}

// scatter voxel index; atomicMax == last-index-wins (matches CPU sequential scatter)
__global__ void k_scatter(const int4* __restrict__ coors, int* __restrict__ grid, int n) {
    int i = blockIdx.x * blockDim.x + threadIdx.x;
    if (i >= n) return;
    int4 c = coors[i];  // (b, z, y, x)
    int flat = ((c.x * SD + c.y) * SH + c.z) * SW + c.w;
    atomicMax(&grid[flat], i);
}

// Voxel-stationary conv, on-the-fly rulebook. One wave = 32 voxels x 64 cout.
// A-frag (16x16x32): lane holds row lane&15, k=(lane>>4)*8+j -> one 16B load.
// C/D: col=lane&15, row=(lane>>4)*4+reg (m89-verified).
template <int IN_F32, int OUT_BF16>
__global__ __launch_bounds__(256) void k_conv(const void* __restrict__ finv,
                                              const s16x8* __restrict__ wt,   // [KV*8*64] frags
                                              const int4* __restrict__ coors,
                                              const int* __restrict__ grid,
                                              void* __restrict__ outp, int n) {
    int wid = blockIdx.x * (blockDim.x >> 6) + (threadIdx.x >> 6);
    int lane = threadIdx.x & 63;
    int base = wid * 32;
    if (base >= n) return;
    int r = lane & 15;
    int g = lane >> 4;

    // this lane owns the neighbor lookups for row base + (lane&31)
    int li = lane & 31;
    int myrow = base + li;
    int rowok = (myrow < n) ? 1 : 0;
    int4 c = coors[rowok ? myrow : 0];
    int z = c.y, y = c.z, x = c.w;
    int flatbase = ((c.x * SD + z) * SH + y) * SW + x;

    f32x4 acc[2][4] = {};

    auto lookup = [&](int k) -> int {
        int dz = k / 9 - 1, dy = (k / 3) % 3 - 1, dx = k % 3 - 1;
        int zz = z + dz, yy = y + dy, xx = x + dx;
        int v = -1;
        if (rowok && (unsigned)zz < SD && (unsigned)yy < SH && (unsigned)xx < SW)
            v = grid[flatbase + dz * (SH * SW) + dy * SW + dx];
        return v;
    };

    int nbr = lookup(0);
    for (int k = 0; k < KV; ++k) {
        int nbr_next = (k + 1 < KV) ? lookup(k + 1) : -1;  // prefetch next offset
        int nb0 = __shfl(nbr, r);
        int nb1 = __shfl(nbr, 16 + r);
        nbr = nbr_next;
        unsigned long long m0 = __ballot(nb0 >= 0);
        unsigned long long m1 = __ballot(nb1 >= 0);
        if ((m0 | m1) == 0ULL) continue;

        s16x8 bf[2][4];
#pragma unroll
        for (int s = 0; s < 2; ++s)
#pragma unroll
            for (int t = 0; t < 4; ++t)
                bf[s][t] = wt[(k * 8 + s * 4 + g) * 64 + t * 16 + r];

        int nbh[2] = {nb0, nb1};
        unsigned long long mm[2] = {m0, m1};
#pragma unroll
        for (int h = 0; h < 2; ++h) {
            if (!mm[h]) continue;
            int nbx = nbh[h];
            s16x8 a0 = {}, a1 = {};
            if (nbx >= 0) {
                if (IN_F32) {
                    const float4* ff = (const float4*)finv;  // row = 16 float4
                    size_t rb = (size_t)nbx * 16 + g * 2;
                    float4 p0 = ff[rb], p1 = ff[rb + 1];
                    float4 p2 = ff[rb + 8], p3 = ff[rb + 9];
                    a0 = pack_bf8(p0, p1);
                    a1 = pack_bf8(p2, p3);
                } else {
                    const s16x8* fb = (const s16x8*)finv;    // row = 8 x s16x8
                    a0 = fb[(size_t)nbx * 8 + g];
                    a1 = fb[(size_t)nbx * 8 + 4 + g];
                }
            }
#pragma unroll
            for (int t = 0; t < 4; ++t) {
                acc[h][t] = __builtin_amdgcn_mfma_f32_16x16x32_bf16(a0, bf[0][t], acc[h][t], 0, 0, 0);
                acc[h][t] = __builtin_amdgcn_mfma_f32_16x16x32_bf16(a1, bf[1][t], acc[h][t], 0, 0, 0);
            }
        }
    }

    if (OUT_BF16) {
        unsigned short* __restrict__ o = (unsigned short*)outp;
#pragma unroll
        for (int h = 0; h < 2; ++h)
#pragma unroll
            for (int t = 0; t < 4; ++t)
#pragma unroll
                for (int j = 0; j < 4; ++j) {
                    int row = base + h * 16 + g * 4 + j;
                    if (row < n) o[(size_t)row * 64 + t * 16 + r] = f2bf_rne(acc[h][t][j]);
                }
    } else {
        float* __restrict__ o = (float*)outp;
#pragma unroll
        for (int h = 0; h < 2; ++h)
#pragma unroll
            for (int t = 0; t < 4; ++t)
#pragma unroll
                for (int j = 0; j < 4; ++j) {
                    int row = base + h * 16 + g * 4 + j;
                    if (row < n) o[(size_t)row * 64 + t * 16 + r] = acc[h][t][j];
                }
    }
}

extern "C" void kernel_launch(void* const* d_in, const int* in_sizes, int n_in,
                              void* d_out, int out_size, void* d_ws, size_t ws_size,
                              hipStream_t stream) {
    const float* feats = (const float*)d_in[0];
    const int4* coors = (const int4*)d_in[1];
    const float* W0 = (const float*)d_in[2];
    const float* W1 = (const float*)d_in[3];
    int N = in_sizes[0] / CCH;

    char* p = (char*)d_ws;
    auto carve = [&](size_t bytes) -> char* {
        char* q = p;
        p += (bytes + 255) & ~(size_t)255;
        return q;
    };
    size_t grid_bytes = (size_t)BATCH * SD * SH * SW * 4;   // 16.78 MB
    int* grid = (int*)carve(grid_bytes);
    unsigned short* wt0 = (unsigned short*)carve((size_t)KV * CCH * CCH * 2);
    unsigned short* wt1 = (unsigned short*)carve((size_t)KV * CCH * CCH * 2);
    s16x8* ibf = (s16x8*)carve((size_t)N * CCH * 2);        // 25.6 MB bf16 intermediate
    size_t base_need = (size_t)(p - (char*)d_ws);
    // optional bf16 feature copy if workspace allows (+25.6 MB)
    s16x8* fbf = nullptr;
    if (ws_size >= base_need + (size_t)N * CCH * 2 + 256)
        fbf = (s16x8*)carve((size_t)N * CCH * 2);

    hipMemsetAsync(grid, 0xFF, grid_bytes, stream);

    int nw = KV * CCH * CCH;
    k_wprep<<<(nw + 255) / 256, 256, 0, stream>>>(W0, wt0);
    k_wprep<<<(nw + 255) / 256, 256, 0, stream>>>(W1, wt1);
    k_scatter<<<(N + 255) / 256, 256, 0, stream>>>(coors, grid, N);

    int tiles = (N + 31) / 32;
    int blocks = (tiles + 3) / 4;
    if (fbf) {
        int n4 = N * CCH / 4;
        k_f2bf<<<(n4 + 255) / 256, 256, 0, stream>>>((const float4*)feats, (ushort4*)fbf, n4);
        k_conv<0, 1><<<blocks, 256, 0, stream>>>(fbf, (const s16x8*)wt0, coors, grid, ibf, N);
    } else {
        k_conv<1, 1><<<blocks, 256, 0, stream>>>(feats, (const s16x8*)wt0, coors, grid, ibf, N);
    }
    k_conv<0, 0><<<blocks, 256, 0, stream>>>(ibf, (const s16x8*)wt1, coors, grid, d_out, N);
}